// Round 1
// baseline (3183.859 us; speedup 1.0000x reference)
//
#include <hip/hip_runtime.h>

#define N_NODES 100000
#define N_EDGES 800000
#define DIM 64
#define HEADS 4
// Dh = 16

// ---------------------------------------------------------------------------
// Kernel 1: per-node projections Q = E*Wq, K = E*Wk, V = E*Wv  (N x 64)
// Block = 256 threads: thread t handles (sub = t>>6, col = t&63); each block
// iterates over groups of 4 nodes. W matrices staged in LDS (48 KB).
// ---------------------------------------------------------------------------
__global__ __launch_bounds__(256) void qkv_kernel(
    const float* __restrict__ embeds,
    const float* __restrict__ Wq,
    const float* __restrict__ Wk,
    const float* __restrict__ Wv,
    float* __restrict__ Q,
    float* __restrict__ K,
    float* __restrict__ V)
{
    __shared__ float sW[3][DIM][DIM];   // 48 KB
    __shared__ float sE[4][DIM];        // 1 KB

    const int t = threadIdx.x;
    for (int i = t; i < DIM * DIM; i += 256) {
        sW[0][i >> 6][i & 63] = Wq[i];
        sW[1][i >> 6][i & 63] = Wk[i];
        sW[2][i >> 6][i & 63] = Wv[i];
    }
    __syncthreads();

    const int col = t & 63;
    const int sub = t >> 6;
    const int lrow = t >> 6, lcol = t & 63;
    const int ngroups = (N_NODES + 3) >> 2;

    for (int g = blockIdx.x; g < ngroups; g += gridDim.x) {
        const int nbase = g << 2;
        const int node_l = nbase + lrow;
        sE[lrow][lcol] = (node_l < N_NODES) ? embeds[node_l * DIM + lcol] : 0.0f;
        __syncthreads();

        const int node = nbase + sub;
        float aq = 0.0f, ak = 0.0f, av = 0.0f;
        #pragma unroll
        for (int kk = 0; kk < DIM; ++kk) {
            const float e = sE[sub][kk];                    // broadcast within 64-lane group
            aq = fmaf(e, sW[0][kk][col], aq);               // stride-1 over lanes: 2-way bank alias = free
            ak = fmaf(e, sW[1][kk][col], ak);
            av = fmaf(e, sW[2][kk][col], av);
        }
        if (node < N_NODES) {
            Q[node * DIM + col] = aq;
            K[node * DIM + col] = ak;
            V[node * DIM + col] = av;
        }
        __syncthreads();
    }
}

// ---------------------------------------------------------------------------
// Kernel 2: per (edge, head): raw attention score -> exp -> scatter-add norm
// expAtt written straight into the att-output region of d_out.
// ---------------------------------------------------------------------------
__global__ __launch_bounds__(256) void edge_att_kernel(
    const float* __restrict__ Q,
    const float* __restrict__ K,
    const int* __restrict__ rows,
    const int* __restrict__ cols,
    float* __restrict__ expAtt,      // [E, 4]
    float* __restrict__ norm)        // [N, 4]
{
    const int tid = blockIdx.x * 256 + threadIdx.x;
    const int e = tid >> 2;
    const int h = tid & 3;
    if (e >= N_EDGES) return;

    const int r = rows[e];
    const int c = cols[e];

    const float4* qv = (const float4*)(Q + (size_t)r * DIM + h * 16);
    const float4* kv = (const float4*)(K + (size_t)c * DIM + h * 16);

    float s = 0.0f;
    #pragma unroll
    for (int i = 0; i < 4; ++i) {
        const float4 a = qv[i];
        const float4 b = kv[i];
        s += a.x * b.x + a.y * b.y + a.z * b.z + a.w * b.w;
    }
    s = fminf(fmaxf(s, -10.0f), 10.0f);
    const float ex = __expf(s);

    expAtt[(size_t)e * HEADS + h] = ex;
    atomicAdd(&norm[(size_t)r * HEADS + h], ex);
}

// ---------------------------------------------------------------------------
// Kernel 3: per (edge, head): normalize att (in-place -> output), accumulate
// res[row] += att * V[col] with 16 scalar f32 atomics per thread.
// ---------------------------------------------------------------------------
__global__ __launch_bounds__(256) void edge_agg_kernel(
    const float* __restrict__ V,
    const int* __restrict__ rows,
    const int* __restrict__ cols,
    const float* __restrict__ norm,
    float* __restrict__ attOut,      // [E, 4] in/out (expAtt -> normalized)
    float* __restrict__ res)         // [N, 64], pre-zeroed
{
    const int tid = blockIdx.x * 256 + threadIdx.x;
    const int e = tid >> 2;
    const int h = tid & 3;
    if (e >= N_EDGES) return;

    const int r = rows[e];
    const int c = cols[e];

    const float ex = attOut[(size_t)e * HEADS + h];
    const float a = ex / (norm[(size_t)r * HEADS + h] + 1e-8f);
    attOut[(size_t)e * HEADS + h] = a;

    const float4* vv = (const float4*)(V + (size_t)c * DIM + h * 16);
    float* rp = res + (size_t)r * DIM + h * 16;
    #pragma unroll
    for (int i = 0; i < 4; ++i) {
        const float4 vi = vv[i];
        atomicAdd(rp + i * 4 + 0, a * vi.x);
        atomicAdd(rp + i * 4 + 1, a * vi.y);
        atomicAdd(rp + i * 4 + 2, a * vi.z);
        atomicAdd(rp + i * 4 + 3, a * vi.w);
    }
}

// ---------------------------------------------------------------------------

extern "C" void kernel_launch(void* const* d_in, const int* in_sizes, int n_in,
                              void* d_out, int out_size, void* d_ws, size_t ws_size,
                              hipStream_t stream) {
    const float* embeds = (const float*)d_in[0];
    const float* Wq     = (const float*)d_in[1];
    const float* Wk     = (const float*)d_in[2];
    const float* Wv     = (const float*)d_in[3];
    const int*   rows   = (const int*)d_in[4];
    const int*   cols   = (const int*)d_in[5];

    float* out    = (float*)d_out;
    float* res    = out;                                 // [N, 64]
    float* attOut = out + (size_t)N_NODES * DIM;         // [E, 4]

    float* Q    = (float*)d_ws;                          // [N, 64]
    float* K    = Q + (size_t)N_NODES * DIM;             // [N, 64]
    float* V    = K + (size_t)N_NODES * DIM;             // [N, 64]
    float* norm = V + (size_t)N_NODES * DIM;             // [N, 4]

    // zero the accumulation targets (harness poisons d_out/d_ws with 0xAA)
    hipMemsetAsync(res,  0, (size_t)N_NODES * DIM * sizeof(float), stream);
    hipMemsetAsync(norm, 0, (size_t)N_NODES * HEADS * sizeof(float), stream);

    qkv_kernel<<<1024, 256, 0, stream>>>(embeds, Wq, Wk, Wv, Q, K, V);

    const int tot = N_EDGES * HEADS;
    const int blocks = (tot + 255) / 256;
    edge_att_kernel<<<blocks, 256, 0, stream>>>(Q, K, rows, cols, attOut, norm);
    edge_agg_kernel<<<blocks, 256, 0, stream>>>(V, rows, cols, norm, attOut, res);
}

// Round 2
// 632.641 us; speedup vs baseline: 5.0327x; 5.0327x over previous
//
#include <hip/hip_runtime.h>

#define N_NODES 100000
#define N_EDGES 800000
#define DIM 64
#define HEADS 4

// ---------------------------------------------------------------------------
// Kernel 1: per-node projections Q = E*Wq, K = E*Wk, V = E*Wv  (N x 64)
// ---------------------------------------------------------------------------
__global__ __launch_bounds__(256) void qkv_kernel(
    const float* __restrict__ embeds,
    const float* __restrict__ Wq,
    const float* __restrict__ Wk,
    const float* __restrict__ Wv,
    float* __restrict__ Q,
    float* __restrict__ K,
    float* __restrict__ V)
{
    __shared__ float sW[3][DIM][DIM];   // 48 KB
    __shared__ float sE[4][DIM];        // 1 KB

    const int t = threadIdx.x;
    for (int i = t; i < DIM * DIM; i += 256) {
        sW[0][i >> 6][i & 63] = Wq[i];
        sW[1][i >> 6][i & 63] = Wk[i];
        sW[2][i >> 6][i & 63] = Wv[i];
    }
    __syncthreads();

    const int col = t & 63;
    const int sub = t >> 6;
    const int ngroups = (N_NODES + 3) >> 2;

    for (int g = blockIdx.x; g < ngroups; g += gridDim.x) {
        const int nbase = g << 2;
        const int node_l = nbase + sub;
        sE[sub][col] = (node_l < N_NODES) ? embeds[node_l * DIM + col] : 0.0f;
        __syncthreads();

        const int node = nbase + sub;
        float aq = 0.0f, ak = 0.0f, av = 0.0f;
        #pragma unroll
        for (int kk = 0; kk < DIM; ++kk) {
            const float e = sE[sub][kk];
            aq = fmaf(e, sW[0][kk][col], aq);
            ak = fmaf(e, sW[1][kk][col], ak);
            av = fmaf(e, sW[2][kk][col], av);
        }
        if (node < N_NODES) {
            Q[node * DIM + col] = aq;
            K[node * DIM + col] = ak;
            V[node * DIM + col] = av;
        }
        __syncthreads();
    }
}

// ---------------------------------------------------------------------------
// CSR construction: histogram -> single-block scan -> scatter
// ---------------------------------------------------------------------------
__global__ __launch_bounds__(256) void hist_kernel(
    const int* __restrict__ rows, int* __restrict__ counts)
{
    const int e = blockIdx.x * 256 + threadIdx.x;
    if (e < N_EDGES) atomicAdd(&counts[rows[e]], 1);
}

__global__ __launch_bounds__(1024) void scan_kernel(
    const int* __restrict__ counts,
    int* __restrict__ offsets,
    int* __restrict__ cursor)
{
    __shared__ int sums[1024];
    const int t = threadIdx.x;
    const int chunk = (N_NODES + 1023) / 1024;   // 98
    const int base = t * chunk;

    int s = 0;
    for (int i = 0; i < chunk; ++i) {
        const int idx = base + i;
        if (idx < N_NODES) s += counts[idx];
    }
    sums[t] = s;
    __syncthreads();
    for (int off = 1; off < 1024; off <<= 1) {
        const int add = (t >= off) ? sums[t - off] : 0;
        __syncthreads();
        sums[t] += add;
        __syncthreads();
    }
    int run = (t == 0) ? 0 : sums[t - 1];
    for (int i = 0; i < chunk; ++i) {
        const int idx = base + i;
        if (idx < N_NODES) {
            offsets[idx] = run;
            cursor[idx]  = run;
            run += counts[idx];
        }
    }
}

__global__ __launch_bounds__(256) void scatter_kernel(
    const int* __restrict__ rows,
    const int* __restrict__ cols,
    int* __restrict__ cursor,
    int* __restrict__ sortedCol,
    int* __restrict__ sortedEid)
{
    const int e = blockIdx.x * 256 + threadIdx.x;
    if (e < N_EDGES) {
        const int r = rows[e];
        const int pos = atomicAdd(&cursor[r], 1);
        sortedCol[pos] = cols[e];
        sortedEid[pos] = e;
    }
}

// ---------------------------------------------------------------------------
// Fused per-node aggregation: one 64-lane wave per node.
// Phase A (lane = slot*4+h): s = q.k, exp, store expAtt, accumulate norm.
//   Inline PV (lane = dim):  acc[dim] += shfl(expAtt) * V[col, dim].
// Epilogue: shfl-reduce norm over slots; res = acc/(norm+eps) (1 write/node).
// Phase B: rescale attOut in place by 1/(norm+eps).   ZERO atomics.
// ---------------------------------------------------------------------------
__global__ __launch_bounds__(256) void node_agg_kernel(
    const float* __restrict__ Q,
    const float* __restrict__ K,
    const float* __restrict__ V,
    const int* __restrict__ offsets,
    const int* __restrict__ counts,
    const int* __restrict__ sortedCol,
    const int* __restrict__ sortedEid,
    float* __restrict__ attOut,      // [E,4]: expAtt then normalized in-place
    float* __restrict__ res)         // [N,64]
{
    const int gtid = blockIdx.x * 256 + threadIdx.x;
    const int node = gtid >> 6;
    const int lane = threadIdx.x & 63;
    if (node >= N_NODES) return;

    const int start = offsets[node];
    const int cnt   = counts[node];

    const int slot = lane >> 2;      // 0..15
    const int h    = lane & 3;       // 0..3
    const int hd   = lane >> 4;      // head owning dim=lane

    // q fragment for head h (16 floats)
    const float4* qp = (const float4*)(Q + (size_t)node * DIM + h * 16);
    const float4 q0 = qp[0], q1 = qp[1], q2 = qp[2], q3 = qp[3];

    float normacc = 0.0f;            // per (slot,h) partial of sum(expAtt)
    float acc     = 0.0f;            // PV accumulator for dim = lane

    for (int cbase = 0; cbase < cnt; cbase += 16) {
        const int j = cbase + slot;
        const bool active = (j < cnt);
        int col = 0;
        float ex = 0.0f;
        if (active) {
            col = sortedCol[start + j];
            const int eid = sortedEid[start + j];
            const float4* kp = (const float4*)(K + (size_t)col * DIM + h * 16);
            const float4 k0 = kp[0], k1 = kp[1], k2 = kp[2], k3 = kp[3];
            float s = q0.x*k0.x + q0.y*k0.y + q0.z*k0.z + q0.w*k0.w
                    + q1.x*k1.x + q1.y*k1.y + q1.z*k1.z + q1.w*k1.w
                    + q2.x*k2.x + q2.y*k2.y + q2.z*k2.z + q2.w*k2.w
                    + q3.x*k3.x + q3.y*k3.y + q3.z*k3.z + q3.w*k3.w;
            s = fminf(fmaxf(s, -10.0f), 10.0f);
            ex = __expf(s);
            attOut[(size_t)eid * HEADS + h] = ex;
        }
        normacc += ex;

        // PV accumulation: lane acts as dim; walk this chunk's edges
        const int m = (cnt - cbase < 16) ? (cnt - cbase) : 16;
        for (int s2 = 0; s2 < m; ++s2) {
            const float attv = __shfl(ex, s2 * 4 + hd, 64);
            const int   c2   = __shfl(col, s2 * 4, 64);
            acc += attv * V[(size_t)c2 * DIM + lane];
        }
    }

    // reduce norm over the 16 slots (lanes with equal h are stride-4 apart)
    for (int m2 = 4; m2 <= 32; m2 <<= 1)
        normacc += __shfl_xor(normacc, m2, 64);
    // lane now holds norm for its own h = lane&3

    // res: lane=dim needs norm of head hd; lane hd (0..3) holds head hd's norm
    const float normForDim = __shfl(normacc, hd, 64);
    res[(size_t)node * DIM + lane] = acc / (normForDim + 1e-8f);

    // Phase B: normalize attOut in place ((slot,h) lanes)
    const float inv = 1.0f / (normacc + 1e-8f);
    for (int cbase = 0; cbase < cnt; cbase += 16) {
        const int j = cbase + slot;
        if (j < cnt) {
            const int eid = sortedEid[start + j];
            attOut[(size_t)eid * HEADS + h] *= inv;
        }
    }
}

// ---------------------------------------------------------------------------

extern "C" void kernel_launch(void* const* d_in, const int* in_sizes, int n_in,
                              void* d_out, int out_size, void* d_ws, size_t ws_size,
                              hipStream_t stream) {
    const float* embeds = (const float*)d_in[0];
    const float* Wq     = (const float*)d_in[1];
    const float* Wk     = (const float*)d_in[2];
    const float* Wv     = (const float*)d_in[3];
    const int*   rows   = (const int*)d_in[4];
    const int*   cols   = (const int*)d_in[5];

    float* out    = (float*)d_out;
    float* res    = out;                                 // [N, 64]
    float* attOut = out + (size_t)N_NODES * DIM;         // [E, 4]

    float* Q        = (float*)d_ws;                      // [N,64]
    float* K        = Q + (size_t)N_NODES * DIM;         // [N,64]
    float* V        = K + (size_t)N_NODES * DIM;         // [N,64]
    int*   counts   = (int*)(V + (size_t)N_NODES * DIM); // [N]
    int*   offsets  = counts + N_NODES;                  // [N]
    int*   cursor   = offsets + N_NODES;                 // [N]
    int*   sortedCol= cursor + N_NODES;                  // [E]
    int*   sortedEid= sortedCol + N_EDGES;               // [E]

    hipMemsetAsync(counts, 0, (size_t)N_NODES * sizeof(int), stream);

    qkv_kernel<<<1024, 256, 0, stream>>>(embeds, Wq, Wk, Wv, Q, K, V);

    const int eblocks = (N_EDGES + 255) / 256;
    hist_kernel<<<eblocks, 256, 0, stream>>>(rows, counts);
    scan_kernel<<<1, 1024, 0, stream>>>(counts, offsets, cursor);
    scatter_kernel<<<eblocks, 256, 0, stream>>>(rows, cols, cursor, sortedCol, sortedEid);

    const int nblocks = (N_NODES * 64 + 255) / 256;      // 1 wave per node
    node_agg_kernel<<<nblocks, 256, 0, stream>>>(Q, K, V, offsets, counts,
                                                 sortedCol, sortedEid, attOut, res);
}

// Round 3
// 379.558 us; speedup vs baseline: 8.3883x; 1.6668x over previous
//
#include <hip/hip_runtime.h>

#define N_NODES 100000
#define N_EDGES 800000
#define DIM 64
#define HEADS 4

#define SCAN_BLK 256
#define N_SCAN_BLOCKS ((N_NODES + SCAN_BLK - 1) / SCAN_BLK)   // 391

// ---------------------------------------------------------------------------
// Kernel 1: per-node projections Q = E*Wq, K = E*Wk, V = E*Wv  (N x 64)
// ---------------------------------------------------------------------------
__global__ __launch_bounds__(256) void qkv_kernel(
    const float* __restrict__ embeds,
    const float* __restrict__ Wq,
    const float* __restrict__ Wk,
    const float* __restrict__ Wv,
    float* __restrict__ Q,
    float* __restrict__ K,
    float* __restrict__ V)
{
    __shared__ float sW[3][DIM][DIM];   // 48 KB
    __shared__ float sE[4][DIM];        // 1 KB

    const int t = threadIdx.x;
    for (int i = t; i < DIM * DIM; i += 256) {
        sW[0][i >> 6][i & 63] = Wq[i];
        sW[1][i >> 6][i & 63] = Wk[i];
        sW[2][i >> 6][i & 63] = Wv[i];
    }
    __syncthreads();

    const int col = t & 63;
    const int sub = t >> 6;
    const int ngroups = (N_NODES + 3) >> 2;

    for (int g = blockIdx.x; g < ngroups; g += gridDim.x) {
        const int nbase = g << 2;
        const int node_l = nbase + sub;
        sE[sub][col] = (node_l < N_NODES) ? embeds[node_l * DIM + col] : 0.0f;
        __syncthreads();

        const int node = nbase + sub;
        float aq = 0.0f, ak = 0.0f, av = 0.0f;
        #pragma unroll
        for (int kk = 0; kk < DIM; ++kk) {
            const float e = sE[sub][kk];
            aq = fmaf(e, sW[0][kk][col], aq);
            ak = fmaf(e, sW[1][kk][col], ak);
            av = fmaf(e, sW[2][kk][col], av);
        }
        if (node < N_NODES) {
            Q[node * DIM + col] = aq;
            K[node * DIM + col] = ak;
            V[node * DIM + col] = av;
        }
        __syncthreads();
    }
}

// ---------------------------------------------------------------------------
// CSR construction: histogram -> 3-stage parallel scan -> scatter
// ---------------------------------------------------------------------------
__global__ __launch_bounds__(256) void hist_kernel(
    const int* __restrict__ rows, int* __restrict__ counts)
{
    const int e = blockIdx.x * 256 + threadIdx.x;
    if (e < N_EDGES) atomicAdd(&counts[rows[e]], 1);
}

// Stage A: per-block sums of counts
__global__ __launch_bounds__(SCAN_BLK) void scanA_kernel(
    const int* __restrict__ counts, int* __restrict__ blockSums)
{
    __shared__ int tile[SCAN_BLK];
    const int i = blockIdx.x * SCAN_BLK + threadIdx.x;
    tile[threadIdx.x] = (i < N_NODES) ? counts[i] : 0;
    __syncthreads();
    for (int off = SCAN_BLK / 2; off > 0; off >>= 1) {
        if (threadIdx.x < off) tile[threadIdx.x] += tile[threadIdx.x + off];
        __syncthreads();
    }
    if (threadIdx.x == 0) blockSums[blockIdx.x] = tile[0];
}

// Stage B: single-block exclusive scan of the 391 block sums (in place)
__global__ __launch_bounds__(512) void scanB_kernel(int* __restrict__ blockSums)
{
    __shared__ int s[512];
    const int t = threadIdx.x;
    const int v = (t < N_SCAN_BLOCKS) ? blockSums[t] : 0;
    s[t] = v;
    __syncthreads();
    for (int off = 1; off < 512; off <<= 1) {
        const int add = (t >= off) ? s[t - off] : 0;
        __syncthreads();
        s[t] += add;
        __syncthreads();
    }
    if (t < N_SCAN_BLOCKS) blockSums[t] = s[t] - v;   // exclusive
}

// Stage C: per-block local inclusive scan + block prefix -> offsets/cursor
__global__ __launch_bounds__(SCAN_BLK) void scanC_kernel(
    const int* __restrict__ counts,
    const int* __restrict__ blockSums,
    int* __restrict__ offsets,
    int* __restrict__ cursor)
{
    __shared__ int tile[SCAN_BLK];
    const int i = blockIdx.x * SCAN_BLK + threadIdx.x;
    const int v = (i < N_NODES) ? counts[i] : 0;
    tile[threadIdx.x] = v;
    __syncthreads();
    for (int off = 1; off < SCAN_BLK; off <<= 1) {
        const int add = (threadIdx.x >= off) ? tile[threadIdx.x - off] : 0;
        __syncthreads();
        tile[threadIdx.x] += add;
        __syncthreads();
    }
    if (i < N_NODES) {
        const int excl = tile[threadIdx.x] - v + blockSums[blockIdx.x];
        offsets[i] = excl;
        cursor[i]  = excl;
    }
}

__global__ __launch_bounds__(256) void scatter_kernel(
    const int* __restrict__ rows,
    const int* __restrict__ cols,
    int* __restrict__ cursor,
    int* __restrict__ sortedCol,
    int* __restrict__ sortedEid)
{
    const int e = blockIdx.x * 256 + threadIdx.x;
    if (e < N_EDGES) {
        const int r = rows[e];
        const int pos = atomicAdd(&cursor[r], 1);
        sortedCol[pos] = cols[e];
        sortedEid[pos] = e;
    }
}

// ---------------------------------------------------------------------------
// Fused per-node aggregation: one 64-lane wave per node. ZERO atomics.
// ---------------------------------------------------------------------------
__global__ __launch_bounds__(256) void node_agg_kernel(
    const float* __restrict__ Q,
    const float* __restrict__ K,
    const float* __restrict__ V,
    const int* __restrict__ offsets,
    const int* __restrict__ counts,
    const int* __restrict__ sortedCol,
    const int* __restrict__ sortedEid,
    float* __restrict__ attOut,      // [E,4]: expAtt then normalized in-place
    float* __restrict__ res)         // [N,64]
{
    const int gtid = blockIdx.x * 256 + threadIdx.x;
    const int node = gtid >> 6;
    const int lane = threadIdx.x & 63;
    if (node >= N_NODES) return;

    const int start = offsets[node];
    const int cnt   = counts[node];

    const int slot = lane >> 2;      // 0..15
    const int h    = lane & 3;       // 0..3
    const int hd   = lane >> 4;      // head owning dim=lane

    const float4* qp = (const float4*)(Q + (size_t)node * DIM + h * 16);
    const float4 q0 = qp[0], q1 = qp[1], q2 = qp[2], q3 = qp[3];

    float normacc = 0.0f;
    float acc     = 0.0f;

    for (int cbase = 0; cbase < cnt; cbase += 16) {
        const int j = cbase + slot;
        const bool active = (j < cnt);
        int col = 0;
        float ex = 0.0f;
        if (active) {
            col = sortedCol[start + j];
            const int eid = sortedEid[start + j];
            const float4* kp = (const float4*)(K + (size_t)col * DIM + h * 16);
            const float4 k0 = kp[0], k1 = kp[1], k2 = kp[2], k3 = kp[3];
            float s = q0.x*k0.x + q0.y*k0.y + q0.z*k0.z + q0.w*k0.w
                    + q1.x*k1.x + q1.y*k1.y + q1.z*k1.z + q1.w*k1.w
                    + q2.x*k2.x + q2.y*k2.y + q2.z*k2.z + q2.w*k2.w
                    + q3.x*k3.x + q3.y*k3.y + q3.z*k3.z + q3.w*k3.w;
            s = fminf(fmaxf(s, -10.0f), 10.0f);
            ex = __expf(s);
            attOut[(size_t)eid * HEADS + h] = ex;
        }
        normacc += ex;

        const int m = (cnt - cbase < 16) ? (cnt - cbase) : 16;
        for (int s2 = 0; s2 < m; ++s2) {
            const float attv = __shfl(ex, s2 * 4 + hd, 64);
            const int   c2   = __shfl(col, s2 * 4, 64);
            acc += attv * V[(size_t)c2 * DIM + lane];
        }
    }

    for (int m2 = 4; m2 <= 32; m2 <<= 1)
        normacc += __shfl_xor(normacc, m2, 64);

    const float normForDim = __shfl(normacc, hd, 64);
    res[(size_t)node * DIM + lane] = acc / (normForDim + 1e-8f);

    const float inv = 1.0f / (normacc + 1e-8f);
    for (int cbase = 0; cbase < cnt; cbase += 16) {
        const int j = cbase + slot;
        if (j < cnt) {
            const int eid = sortedEid[start + j];
            attOut[(size_t)eid * HEADS + h] *= inv;
        }
    }
}

// ---------------------------------------------------------------------------

extern "C" void kernel_launch(void* const* d_in, const int* in_sizes, int n_in,
                              void* d_out, int out_size, void* d_ws, size_t ws_size,
                              hipStream_t stream) {
    const float* embeds = (const float*)d_in[0];
    const float* Wq     = (const float*)d_in[1];
    const float* Wk     = (const float*)d_in[2];
    const float* Wv     = (const float*)d_in[3];
    const int*   rows   = (const int*)d_in[4];
    const int*   cols   = (const int*)d_in[5];

    float* out    = (float*)d_out;
    float* res    = out;                                 // [N, 64]
    float* attOut = out + (size_t)N_NODES * DIM;         // [E, 4]

    float* Q        = (float*)d_ws;                      // [N,64]
    float* K        = Q + (size_t)N_NODES * DIM;         // [N,64]
    float* V        = K + (size_t)N_NODES * DIM;         // [N,64]
    int*   counts   = (int*)(V + (size_t)N_NODES * DIM); // [N]
    int*   offsets  = counts + N_NODES;                  // [N]
    int*   cursor   = offsets + N_NODES;                 // [N]
    int*   sortedCol= cursor + N_NODES;                  // [E]
    int*   sortedEid= sortedCol + N_EDGES;               // [E]
    int*   blockSums= sortedEid + N_EDGES;               // [391]

    hipMemsetAsync(counts, 0, (size_t)N_NODES * sizeof(int), stream);

    qkv_kernel<<<1024, 256, 0, stream>>>(embeds, Wq, Wk, Wv, Q, K, V);

    const int eblocks = (N_EDGES + 255) / 256;
    hist_kernel<<<eblocks, 256, 0, stream>>>(rows, counts);
    scanA_kernel<<<N_SCAN_BLOCKS, SCAN_BLK, 0, stream>>>(counts, blockSums);
    scanB_kernel<<<1, 512, 0, stream>>>(blockSums);
    scanC_kernel<<<N_SCAN_BLOCKS, SCAN_BLK, 0, stream>>>(counts, blockSums, offsets, cursor);
    scatter_kernel<<<eblocks, 256, 0, stream>>>(rows, cols, cursor, sortedCol, sortedEid);

    const int nblocks = (N_NODES * 64 + 255) / 256;      // 1 wave per node
    node_agg_kernel<<<nblocks, 256, 0, stream>>>(Q, K, V, offsets, counts,
                                                 sortedCol, sortedEid, attOut, res);
}

// Round 4
// 283.009 us; speedup vs baseline: 11.2500x; 1.3411x over previous
//
#include <hip/hip_runtime.h>

#define N_NODES 100000
#define N_EDGES 800000
#define DIM 64
#define HEADS 4

#define SCAN_BLK 256
#define N_SCAN_BLOCKS ((N_NODES + SCAN_BLK - 1) / SCAN_BLK)   // 391

typedef __attribute__((ext_vector_type(8))) short bf16x8;
typedef __attribute__((ext_vector_type(4))) float f32x4;

__device__ __forceinline__ short f2bf(float x) {
    union { float f; unsigned u; } v; v.f = x;
    unsigned r = (v.u + 0x7FFFu + ((v.u >> 16) & 1u)) >> 16;   // RNE
    return (short)r;
}
__device__ __forceinline__ float bf2f(short b) {
    union { float f; unsigned u; } v; v.u = ((unsigned)(unsigned short)b) << 16;
    return v.f;
}

// ---------------------------------------------------------------------------
// wprep: pack [Wq|Wk|Wv] (64x192) into MFMA B-fragment order, hi+lo bf16.
// Frag layout: idx = ((nt*2+kt)*64 + lane)*8 + j
//   k = kt*32 + (lane>>4)*8 + j ; col192 = nt*16 + (lane&15)
// ---------------------------------------------------------------------------
__global__ __launch_bounds__(256) void wprep_kernel(
    const float* __restrict__ Wq, const float* __restrict__ Wk,
    const float* __restrict__ Wv,
    short* __restrict__ wfragH, short* __restrict__ wfragL)
{
    const int idx = blockIdx.x * 256 + threadIdx.x;
    if (idx >= 12288) return;
    const int j    = idx & 7;
    const int lane = (idx >> 3) & 63;
    const int kt   = (idx >> 9) & 1;
    const int nt   = idx >> 10;
    const int k      = kt * 32 + (lane >> 4) * 8 + j;
    const int col192 = nt * 16 + (lane & 15);
    const float* W = (col192 < 64) ? Wq : ((col192 < 128) ? Wk : Wv);
    const float x = W[k * DIM + (col192 & 63)];
    const short hb = f2bf(x);
    wfragH[idx] = hb;
    wfragL[idx] = f2bf(x - bf2f(hb));
}

// ---------------------------------------------------------------------------
// qkv via MFMA, bf16x3 split (hi*hi + hi*lo + lo*hi) => fp32-level accuracy.
// Block: 256 thr = 4 waves, each wave owns a 16-row M-strip; N=192, K=64.
// ---------------------------------------------------------------------------
__global__ __launch_bounds__(256) void qkv_mfma_kernel(
    const float* __restrict__ embeds,
    const short* __restrict__ wfragH,
    const short* __restrict__ wfragL,
    float* __restrict__ Q, float* __restrict__ K, float* __restrict__ V)
{
    __shared__ __align__(16) short sBH[12288];
    __shared__ __align__(16) short sBL[12288];

    const int t = threadIdx.x;
    {
        const int4* srcH = (const int4*)wfragH;
        const int4* srcL = (const int4*)wfragL;
        int4* dH = (int4*)sBH; int4* dL = (int4*)sBL;
        #pragma unroll
        for (int i = 0; i < 6; ++i) {              // 12288*2B / 16B / 256
            dH[t + 256 * i] = srcH[t + 256 * i];
            dL[t + 256 * i] = srcL[t + 256 * i];
        }
    }
    __syncthreads();

    const int lane = t & 63;
    const int wid  = t >> 6;
    const int m0 = blockIdx.x * 64 + wid * 16;

    int arow = m0 + (lane & 15);
    if (arow >= N_NODES) arow = N_NODES - 1;       // clamp; store is guarded
    const float* ap = embeds + (size_t)arow * DIM + ((lane >> 4) * 8);

    bf16x8 aH[2], aL[2];
    #pragma unroll
    for (int kt = 0; kt < 2; ++kt) {
        const float4 x0 = ((const float4*)(ap + kt * 32))[0];
        const float4 x1 = ((const float4*)(ap + kt * 32))[1];
        const float xs[8] = {x0.x, x0.y, x0.z, x0.w, x1.x, x1.y, x1.z, x1.w};
        bf16x8 h8, l8;
        #pragma unroll
        for (int j = 0; j < 8; ++j) {
            const short hb = f2bf(xs[j]);
            h8[j] = hb;
            l8[j] = f2bf(xs[j] - bf2f(hb));
        }
        aH[kt] = h8; aL[kt] = l8;
    }

    f32x4 acc[12];
    #pragma unroll
    for (int nt = 0; nt < 12; ++nt) acc[nt] = (f32x4){0.f, 0.f, 0.f, 0.f};

    #pragma unroll
    for (int kt = 0; kt < 2; ++kt) {
        #pragma unroll
        for (int nt = 0; nt < 12; ++nt) {
            const int o = ((nt * 2 + kt) * 64 + lane) * 8;
            const bf16x8 bH = *(const bf16x8*)(sBH + o);
            const bf16x8 bL = *(const bf16x8*)(sBL + o);
            acc[nt] = __builtin_amdgcn_mfma_f32_16x16x32_bf16(aH[kt], bH, acc[nt], 0, 0, 0);
            acc[nt] = __builtin_amdgcn_mfma_f32_16x16x32_bf16(aH[kt], bL, acc[nt], 0, 0, 0);
            acc[nt] = __builtin_amdgcn_mfma_f32_16x16x32_bf16(aL[kt], bH, acc[nt], 0, 0, 0);
        }
    }

    // C/D layout: col = lane&15, row = m0 + (lane>>4)*4 + reg   [m89-verified]
    const int rbase = m0 + (lane >> 4) * 4;
    const int cl = lane & 15;
    #pragma unroll
    for (int nt = 0; nt < 12; ++nt) {
        const int col192 = nt * 16 + cl;
        float* dst = (col192 < 64) ? Q : ((col192 < 128) ? K : V);
        const int c = col192 & 63;
        #pragma unroll
        for (int r = 0; r < 4; ++r) {
            const int row = rbase + r;
            if (row < N_NODES) dst[(size_t)row * DIM + c] = acc[nt][r];
        }
    }
}

// ---------------------------------------------------------------------------
// CSR construction: histogram -> 3-stage parallel scan -> scatter (int2 pack)
// ---------------------------------------------------------------------------
__global__ __launch_bounds__(256) void hist_kernel(
    const int* __restrict__ rows, int* __restrict__ counts)
{
    const int e = blockIdx.x * 256 + threadIdx.x;
    if (e < N_EDGES) atomicAdd(&counts[rows[e]], 1);
}

__global__ __launch_bounds__(SCAN_BLK) void scanA_kernel(
    const int* __restrict__ counts, int* __restrict__ blockSums)
{
    __shared__ int tile[SCAN_BLK];
    const int i = blockIdx.x * SCAN_BLK + threadIdx.x;
    tile[threadIdx.x] = (i < N_NODES) ? counts[i] : 0;
    __syncthreads();
    for (int off = SCAN_BLK / 2; off > 0; off >>= 1) {
        if (threadIdx.x < off) tile[threadIdx.x] += tile[threadIdx.x + off];
        __syncthreads();
    }
    if (threadIdx.x == 0) blockSums[blockIdx.x] = tile[0];
}

__global__ __launch_bounds__(512) void scanB_kernel(int* __restrict__ blockSums)
{
    __shared__ int s[512];
    const int t = threadIdx.x;
    const int v = (t < N_SCAN_BLOCKS) ? blockSums[t] : 0;
    s[t] = v;
    __syncthreads();
    for (int off = 1; off < 512; off <<= 1) {
        const int add = (t >= off) ? s[t - off] : 0;
        __syncthreads();
        s[t] += add;
        __syncthreads();
    }
    if (t < N_SCAN_BLOCKS) blockSums[t] = s[t] - v;   // exclusive
}

__global__ __launch_bounds__(SCAN_BLK) void scanC_kernel(
    const int* __restrict__ counts,
    const int* __restrict__ blockSums,
    int* __restrict__ offsets,
    int* __restrict__ cursor)
{
    __shared__ int tile[SCAN_BLK];
    const int i = blockIdx.x * SCAN_BLK + threadIdx.x;
    const int v = (i < N_NODES) ? counts[i] : 0;
    tile[threadIdx.x] = v;
    __syncthreads();
    for (int off = 1; off < SCAN_BLK; off <<= 1) {
        const int add = (threadIdx.x >= off) ? tile[threadIdx.x - off] : 0;
        __syncthreads();
        tile[threadIdx.x] += add;
        __syncthreads();
    }
    if (i < N_NODES) {
        const int excl = tile[threadIdx.x] - v + blockSums[blockIdx.x];
        offsets[i] = excl;
        cursor[i]  = excl;
    }
}

__global__ __launch_bounds__(256) void scatter_kernel(
    const int* __restrict__ rows,
    const int* __restrict__ cols,
    int* __restrict__ cursor,
    int2* __restrict__ sortedPair)
{
    const int e = blockIdx.x * 256 + threadIdx.x;
    if (e < N_EDGES) {
        const int r = rows[e];
        const int pos = atomicAdd(&cursor[r], 1);
        sortedPair[pos] = make_int2(cols[e], e);
    }
}

// ---------------------------------------------------------------------------
// Fused per-node aggregation: 1 wave/node. Unconditional 16-wide PV with
// 16 independent V loads in flight; cols broadcast via readlane (SGPR base).
// Writes expAtt (edge order), norm[node,4], res[node,64]. Zero atomics.
// ---------------------------------------------------------------------------
__global__ __launch_bounds__(256) void node_agg_kernel(
    const float* __restrict__ Q,
    const float* __restrict__ K,
    const float* __restrict__ V,
    const int* __restrict__ offsets,
    const int* __restrict__ counts,
    const int2* __restrict__ sortedPair,
    float* __restrict__ attOut,      // [E,4] expAtt (unnormalized)
    float* __restrict__ normArr,     // [N,4]
    float* __restrict__ res)         // [N,64]
{
    const int node = (blockIdx.x * 256 + threadIdx.x) >> 6;
    const int lane = threadIdx.x & 63;
    if (node >= N_NODES) return;

    const int start = offsets[node];
    const int cnt   = counts[node];

    const int slot = lane >> 2;      // 0..15
    const int h    = lane & 3;       // 0..3
    const int hd   = lane >> 4;      // head owning dim=lane

    const float4* qp = (const float4*)(Q + (size_t)node * DIM + h * 16);
    const float4 q0 = qp[0], q1 = qp[1], q2 = qp[2], q3 = qp[3];

    float normacc = 0.0f;
    float acc     = 0.0f;

    for (int cb = 0; cb < cnt; cb += 16) {
        const int jj = cb + slot;
        const bool active = (jj < cnt);
        int2 pr = make_int2(0, 0);
        if (active) pr = sortedPair[start + jj];
        const int col = pr.x;

        const float4* kp = (const float4*)(K + (size_t)col * DIM + h * 16);
        const float4 k0 = kp[0], k1 = kp[1], k2 = kp[2], k3 = kp[3];
        float s = q0.x*k0.x + q0.y*k0.y + q0.z*k0.z + q0.w*k0.w
                + q1.x*k1.x + q1.y*k1.y + q1.z*k1.z + q1.w*k1.w
                + q2.x*k2.x + q2.y*k2.y + q2.z*k2.z + q2.w*k2.w
                + q3.x*k3.x + q3.y*k3.y + q3.z*k3.z + q3.w*k3.w;
        s = fminf(fmaxf(s, -10.0f), 10.0f);
        const float ex = active ? __expf(s) : 0.0f;
        if (active) attOut[(size_t)pr.y * HEADS + h] = ex;
        normacc += ex;

        // PV: 16 edges, loads issued before use (16 outstanding)
        float vv[16];
        #pragma unroll
        for (int s2 = 0; s2 < 16; ++s2) {
            const int c2 = __builtin_amdgcn_readlane(col, s2 * 4);
            vv[s2] = V[(size_t)c2 * DIM + lane];
        }
        #pragma unroll
        for (int s2 = 0; s2 < 16; ++s2) {
            acc = fmaf(__shfl(ex, s2 * 4 + hd, 64), vv[s2], acc);
        }
    }

    #pragma unroll
    for (int m2 = 4; m2 <= 32; m2 <<= 1)
        normacc += __shfl_xor(normacc, m2, 64);
    // lane now holds total norm for its h = lane&3

    if (lane < 4) normArr[(size_t)node * HEADS + lane] = normacc;

    const float nrm = __shfl(normacc, hd, 64);
    res[(size_t)node * DIM + lane] = acc / (nrm + 1e-8f);
}

// ---------------------------------------------------------------------------
// Edge-parallel normalization of attOut (coalesced R/W + 16B norm gather)
// ---------------------------------------------------------------------------
__global__ __launch_bounds__(256) void norm_edge_kernel(
    const int* __restrict__ rows,
    const float* __restrict__ normArr,
    float* __restrict__ attOut)
{
    const int tid = blockIdx.x * 256 + threadIdx.x;   // (e,h)
    const int e = tid >> 2, h = tid & 3;
    if (e >= N_EDGES) return;
    const float ex = attOut[tid];
    const int r = rows[e];
    attOut[tid] = ex / (normArr[(size_t)r * HEADS + h] + 1e-8f);
}

// ---------------------------------------------------------------------------

extern "C" void kernel_launch(void* const* d_in, const int* in_sizes, int n_in,
                              void* d_out, int out_size, void* d_ws, size_t ws_size,
                              hipStream_t stream) {
    const float* embeds = (const float*)d_in[0];
    const float* Wq     = (const float*)d_in[1];
    const float* Wk     = (const float*)d_in[2];
    const float* Wv     = (const float*)d_in[3];
    const int*   rows   = (const int*)d_in[4];
    const int*   cols   = (const int*)d_in[5];

    float* out    = (float*)d_out;
    float* res    = out;                                 // [N, 64]
    float* attOut = out + (size_t)N_NODES * DIM;         // [E, 4]

    float* Q         = (float*)d_ws;                     // [N,64]
    float* K         = Q + (size_t)N_NODES * DIM;        // [N,64]
    float* V         = K + (size_t)N_NODES * DIM;        // [N,64]
    int*   counts    = (int*)(V + (size_t)N_NODES * DIM);// [N]
    int*   offsets   = counts + N_NODES;                 // [N]
    int*   cursor    = offsets + N_NODES;                // [N]
    int2*  sortedPair= (int2*)(cursor + N_NODES);        // [E] (8B-aligned)
    int*   blockSums = (int*)(sortedPair + N_EDGES);     // [391] (pad to 512)
    short* wfragH    = (short*)(blockSums + 512);        // [12288]
    short* wfragL    = wfragH + 12288;                   // [12288]
    float* normArr   = (float*)(wfragL + 12288);         // [N,4]

    hipMemsetAsync(counts, 0, (size_t)N_NODES * sizeof(int), stream);

    wprep_kernel<<<48, 256, 0, stream>>>(Wq, Wk, Wv, wfragH, wfragL);
    qkv_mfma_kernel<<<(N_NODES + 63) / 64, 256, 0, stream>>>(embeds, wfragH, wfragL, Q, K, V);

    const int eblocks = (N_EDGES + 255) / 256;
    hist_kernel<<<eblocks, 256, 0, stream>>>(rows, counts);
    scanA_kernel<<<N_SCAN_BLOCKS, SCAN_BLK, 0, stream>>>(counts, blockSums);
    scanB_kernel<<<1, 512, 0, stream>>>(blockSums);
    scanC_kernel<<<N_SCAN_BLOCKS, SCAN_BLK, 0, stream>>>(counts, blockSums, offsets, cursor);
    scatter_kernel<<<eblocks, 256, 0, stream>>>(rows, cols, cursor, sortedPair);

    const int nblocks = (N_NODES * 64 + 255) / 256;      // 1 wave per node
    node_agg_kernel<<<nblocks, 256, 0, stream>>>(Q, K, V, offsets, counts,
                                                 sortedPair, attOut, normArr, res);

    const int hblocks = (N_EDGES * HEADS + 255) / 256;
    norm_edge_kernel<<<hblocks, 256, 0, stream>>>(rows, normArr, attOut);
}

// Round 5
// 231.513 us; speedup vs baseline: 13.7524x; 1.2224x over previous
//
#include <hip/hip_runtime.h>

#define N_NODES 100000
#define N_EDGES 800000
#define DIM 64
#define HEADS 4

#define SCAN_BLK 256
#define N_SCAN_BLOCKS ((N_NODES + SCAN_BLK - 1) / SCAN_BLK)   // 391

typedef __attribute__((ext_vector_type(8))) short bf16x8;
typedef __attribute__((ext_vector_type(4))) float f32x4;

__device__ __forceinline__ short f2bf(float x) {
    union { float f; unsigned u; } v; v.f = x;
    unsigned r = (v.u + 0x7FFFu + ((v.u >> 16) & 1u)) >> 16;   // RNE
    return (short)r;
}
__device__ __forceinline__ float bf2f(short b) {
    union { float f; unsigned u; } v; v.u = ((unsigned)(unsigned short)b) << 16;
    return v.f;
}

// ---------------------------------------------------------------------------
// wprep: pack [Wq|Wk|Wv] (64x192) into MFMA B-fragment order, hi+lo bf16.
// ---------------------------------------------------------------------------
__global__ __launch_bounds__(256) void wprep_kernel(
    const float* __restrict__ Wq, const float* __restrict__ Wk,
    const float* __restrict__ Wv,
    short* __restrict__ wfragH, short* __restrict__ wfragL)
{
    const int idx = blockIdx.x * 256 + threadIdx.x;
    if (idx >= 12288) return;
    const int j    = idx & 7;
    const int lane = (idx >> 3) & 63;
    const int kt   = (idx >> 9) & 1;
    const int nt   = idx >> 10;
    const int k      = kt * 32 + (lane >> 4) * 8 + j;
    const int col192 = nt * 16 + (lane & 15);
    const float* W = (col192 < 64) ? Wq : ((col192 < 128) ? Wk : Wv);
    const float x = W[k * DIM + (col192 & 63)];
    const short hb = f2bf(x);
    wfragH[idx] = hb;
    wfragL[idx] = f2bf(x - bf2f(hb));
}

// ---------------------------------------------------------------------------
// qkv via MFMA, bf16x3 split. Q stored fp32; K,V stored bf16 (halve gathers).
// ---------------------------------------------------------------------------
__global__ __launch_bounds__(256) void qkv_mfma_kernel(
    const float* __restrict__ embeds,
    const short* __restrict__ wfragH,
    const short* __restrict__ wfragL,
    float* __restrict__ Q,
    unsigned short* __restrict__ Kb,
    unsigned short* __restrict__ Vb)
{
    __shared__ __align__(16) short sBH[12288];
    __shared__ __align__(16) short sBL[12288];

    const int t = threadIdx.x;
    {
        const int4* srcH = (const int4*)wfragH;
        const int4* srcL = (const int4*)wfragL;
        int4* dH = (int4*)sBH; int4* dL = (int4*)sBL;
        #pragma unroll
        for (int i = 0; i < 6; ++i) {
            dH[t + 256 * i] = srcH[t + 256 * i];
            dL[t + 256 * i] = srcL[t + 256 * i];
        }
    }
    __syncthreads();

    const int lane = t & 63;
    const int wid  = t >> 6;
    const int m0 = blockIdx.x * 64 + wid * 16;

    int arow = m0 + (lane & 15);
    if (arow >= N_NODES) arow = N_NODES - 1;       // clamp; store is guarded
    const float* ap = embeds + (size_t)arow * DIM + ((lane >> 4) * 8);

    bf16x8 aH[2], aL[2];
    #pragma unroll
    for (int kt = 0; kt < 2; ++kt) {
        const float4 x0 = ((const float4*)(ap + kt * 32))[0];
        const float4 x1 = ((const float4*)(ap + kt * 32))[1];
        const float xs[8] = {x0.x, x0.y, x0.z, x0.w, x1.x, x1.y, x1.z, x1.w};
        bf16x8 h8, l8;
        #pragma unroll
        for (int j = 0; j < 8; ++j) {
            const short hb = f2bf(xs[j]);
            h8[j] = hb;
            l8[j] = f2bf(xs[j] - bf2f(hb));
        }
        aH[kt] = h8; aL[kt] = l8;
    }

    f32x4 acc[12];
    #pragma unroll
    for (int nt = 0; nt < 12; ++nt) acc[nt] = (f32x4){0.f, 0.f, 0.f, 0.f};

    #pragma unroll
    for (int kt = 0; kt < 2; ++kt) {
        #pragma unroll
        for (int nt = 0; nt < 12; ++nt) {
            const int o = ((nt * 2 + kt) * 64 + lane) * 8;
            const bf16x8 bH = *(const bf16x8*)(sBH + o);
            const bf16x8 bL = *(const bf16x8*)(sBL + o);
            acc[nt] = __builtin_amdgcn_mfma_f32_16x16x32_bf16(aH[kt], bH, acc[nt], 0, 0, 0);
            acc[nt] = __builtin_amdgcn_mfma_f32_16x16x32_bf16(aH[kt], bL, acc[nt], 0, 0, 0);
            acc[nt] = __builtin_amdgcn_mfma_f32_16x16x32_bf16(aL[kt], bH, acc[nt], 0, 0, 0);
        }
    }

    // C/D layout: col = lane&15, row = m0 + (lane>>4)*4 + reg
    const int rbase = m0 + (lane >> 4) * 4;
    const int cl = lane & 15;
    #pragma unroll
    for (int nt = 0; nt < 12; ++nt) {
        const int col192 = nt * 16 + cl;
        #pragma unroll
        for (int r = 0; r < 4; ++r) {
            const int row = rbase + r;
            if (row < N_NODES) {
                if (col192 < 64)
                    Q[(size_t)row * DIM + col192] = acc[nt][r];
                else if (col192 < 128)
                    Kb[(size_t)row * DIM + (col192 - 64)] = (unsigned short)f2bf(acc[nt][r]);
                else
                    Vb[(size_t)row * DIM + (col192 - 128)] = (unsigned short)f2bf(acc[nt][r]);
            }
        }
    }
}

// ---------------------------------------------------------------------------
// CSR: hist (+rank) -> 3-stage scan -> atomic-free scatter
// ---------------------------------------------------------------------------
__global__ __launch_bounds__(256) void hist_kernel(
    const int* __restrict__ rows, int* __restrict__ counts,
    int* __restrict__ rank)
{
    const int e = blockIdx.x * 256 + threadIdx.x;
    if (e < N_EDGES) rank[e] = atomicAdd(&counts[rows[e]], 1);
}

__global__ __launch_bounds__(SCAN_BLK) void scanA_kernel(
    const int* __restrict__ counts, int* __restrict__ blockSums)
{
    __shared__ int tile[SCAN_BLK];
    const int i = blockIdx.x * SCAN_BLK + threadIdx.x;
    tile[threadIdx.x] = (i < N_NODES) ? counts[i] : 0;
    __syncthreads();
    for (int off = SCAN_BLK / 2; off > 0; off >>= 1) {
        if (threadIdx.x < off) tile[threadIdx.x] += tile[threadIdx.x + off];
        __syncthreads();
    }
    if (threadIdx.x == 0) blockSums[blockIdx.x] = tile[0];
}

__global__ __launch_bounds__(512) void scanB_kernel(int* __restrict__ blockSums)
{
    __shared__ int s[512];
    const int t = threadIdx.x;
    const int v = (t < N_SCAN_BLOCKS) ? blockSums[t] : 0;
    s[t] = v;
    __syncthreads();
    for (int off = 1; off < 512; off <<= 1) {
        const int add = (t >= off) ? s[t - off] : 0;
        __syncthreads();
        s[t] += add;
        __syncthreads();
    }
    if (t < N_SCAN_BLOCKS) blockSums[t] = s[t] - v;   // exclusive
}

__global__ __launch_bounds__(SCAN_BLK) void scanC_kernel(
    const int* __restrict__ counts,
    const int* __restrict__ blockSums,
    int* __restrict__ offsets)
{
    __shared__ int tile[SCAN_BLK];
    const int i = blockIdx.x * SCAN_BLK + threadIdx.x;
    const int v = (i < N_NODES) ? counts[i] : 0;
    tile[threadIdx.x] = v;
    __syncthreads();
    for (int off = 1; off < SCAN_BLK; off <<= 1) {
        const int add = (threadIdx.x >= off) ? tile[threadIdx.x - off] : 0;
        __syncthreads();
        tile[threadIdx.x] += add;
        __syncthreads();
    }
    if (i < N_NODES) offsets[i] = tile[threadIdx.x] - v + blockSums[blockIdx.x];
}

__global__ __launch_bounds__(256) void scatter_kernel(
    const int* __restrict__ rows,
    const int* __restrict__ cols,
    const int* __restrict__ offsets,
    const int* __restrict__ rank,
    int2* __restrict__ sortedPair)
{
    const int e = blockIdx.x * 256 + threadIdx.x;
    if (e < N_EDGES) {
        const int pos = offsets[rows[e]] + rank[e];
        sortedPair[pos] = make_int2(cols[e], e);
    }
}

// ---------------------------------------------------------------------------
// Fused per-node aggregation: 1 wave/node, bf16 K/V gathers, zero atomics.
// ---------------------------------------------------------------------------
__global__ __launch_bounds__(256) void node_agg_kernel(
    const float* __restrict__ Q,
    const unsigned short* __restrict__ Kb,
    const unsigned short* __restrict__ Vb,
    const int* __restrict__ offsets,
    const int* __restrict__ counts,
    const int2* __restrict__ sortedPair,
    float* __restrict__ attOut,      // [E,4] expAtt (unnormalized)
    float* __restrict__ normArr,     // [N,4]
    float* __restrict__ res)         // [N,64]
{
    const int node = (blockIdx.x * 256 + threadIdx.x) >> 6;
    const int lane = threadIdx.x & 63;
    if (node >= N_NODES) return;

    const int start = offsets[node];
    const int cnt   = counts[node];

    const int slot = lane >> 2;      // 0..15
    const int h    = lane & 3;       // 0..3
    const int hd   = lane >> 4;      // head owning dim=lane

    float qv[16];
    {
        const float4* qp = (const float4*)(Q + (size_t)node * DIM + h * 16);
        ((float4*)qv)[0] = qp[0]; ((float4*)qv)[1] = qp[1];
        ((float4*)qv)[2] = qp[2]; ((float4*)qv)[3] = qp[3];
    }

    float normacc = 0.0f;
    float acc     = 0.0f;

    for (int cb = 0; cb < cnt; cb += 16) {
        const int jj = cb + slot;
        const bool active = (jj < cnt);
        int2 pr = make_int2(0, 0);
        if (active) pr = sortedPair[start + jj];
        const int col = pr.x;

        const unsigned short* kp = Kb + (size_t)col * DIM + h * 16;
        const bf16x8 k0 = *(const bf16x8*)kp;
        const bf16x8 k1 = *(const bf16x8*)(kp + 8);
        float s = 0.0f;
        #pragma unroll
        for (int j = 0; j < 8; ++j) s = fmaf(qv[j], bf2f(k0[j]), s);
        #pragma unroll
        for (int j = 0; j < 8; ++j) s = fmaf(qv[8 + j], bf2f(k1[j]), s);

        s = fminf(fmaxf(s, -10.0f), 10.0f);
        const float ex = active ? __expf(s) : 0.0f;
        if (active) attOut[(size_t)pr.y * HEADS + h] = ex;
        normacc += ex;

        // PV: 16 edges; raw loads first (16 outstanding), then FMAs
        unsigned short raw[16];
        #pragma unroll
        for (int s2 = 0; s2 < 16; ++s2) {
            const int c2 = __builtin_amdgcn_readlane(col, s2 * 4);
            raw[s2] = Vb[(size_t)c2 * DIM + lane];
        }
        #pragma unroll
        for (int s2 = 0; s2 < 16; ++s2) {
            acc = fmaf(__shfl(ex, s2 * 4 + hd, 64), bf2f((short)raw[s2]), acc);
        }
    }

    #pragma unroll
    for (int m2 = 4; m2 <= 32; m2 <<= 1)
        normacc += __shfl_xor(normacc, m2, 64);

    if (lane < 4) normArr[(size_t)node * HEADS + lane] = normacc;

    const float nrm = __shfl(normacc, hd, 64);
    res[(size_t)node * DIM + lane] = acc / (nrm + 1e-8f);
}

// ---------------------------------------------------------------------------
// Edge-parallel normalization of attOut: 1 thread/edge, float4 R/W.
// ---------------------------------------------------------------------------
__global__ __launch_bounds__(256) void norm_edge_kernel(
    const int* __restrict__ rows,
    const float* __restrict__ normArr,
    float* __restrict__ attOut)
{
    const int e = blockIdx.x * 256 + threadIdx.x;
    if (e >= N_EDGES) return;
    float4 ex4 = ((const float4*)attOut)[e];
    const float4 n4 = ((const float4*)normArr)[rows[e]];
    ex4.x /= (n4.x + 1e-8f);
    ex4.y /= (n4.y + 1e-8f);
    ex4.z /= (n4.z + 1e-8f);
    ex4.w /= (n4.w + 1e-8f);
    ((float4*)attOut)[e] = ex4;
}

// ---------------------------------------------------------------------------

extern "C" void kernel_launch(void* const* d_in, const int* in_sizes, int n_in,
                              void* d_out, int out_size, void* d_ws, size_t ws_size,
                              hipStream_t stream) {
    const float* embeds = (const float*)d_in[0];
    const float* Wq     = (const float*)d_in[1];
    const float* Wk     = (const float*)d_in[2];
    const float* Wv     = (const float*)d_in[3];
    const int*   rows   = (const int*)d_in[4];
    const int*   cols   = (const int*)d_in[5];

    float* out    = (float*)d_out;
    float* res    = out;                                 // [N, 64]
    float* attOut = out + (size_t)N_NODES * DIM;         // [E, 4]

    float*          Q         = (float*)d_ws;                       // [N,64] f32
    unsigned short* Kb        = (unsigned short*)(Q + (size_t)N_NODES * DIM);   // [N,64] bf16
    unsigned short* Vb        = Kb + (size_t)N_NODES * DIM;         // [N,64] bf16
    int2*           sortedPair= (int2*)(Vb + (size_t)N_NODES * DIM);// [E]
    int*            counts    = (int*)(sortedPair + N_EDGES);       // [N]
    int*            offsets   = counts + N_NODES;                   // [N]
    int*            rank      = offsets + N_NODES;                  // [E]
    int*            blockSums = rank + N_EDGES;                     // [512]
    short*          wfragH    = (short*)(blockSums + 512);          // [12288]
    short*          wfragL    = wfragH + 12288;                     // [12288]
    float*          normArr   = (float*)(wfragL + 12288);           // [N,4]

    hipMemsetAsync(counts, 0, (size_t)N_NODES * sizeof(int), stream);

    wprep_kernel<<<48, 256, 0, stream>>>(Wq, Wk, Wv, wfragH, wfragL);
    qkv_mfma_kernel<<<(N_NODES + 63) / 64, 256, 0, stream>>>(embeds, wfragH, wfragL, Q, Kb, Vb);

    const int eblocks = (N_EDGES + 255) / 256;
    hist_kernel<<<eblocks, 256, 0, stream>>>(rows, counts, rank);
    scanA_kernel<<<N_SCAN_BLOCKS, SCAN_BLK, 0, stream>>>(counts, blockSums);
    scanB_kernel<<<1, 512, 0, stream>>>(blockSums);
    scanC_kernel<<<N_SCAN_BLOCKS, SCAN_BLK, 0, stream>>>(counts, blockSums, offsets);
    scatter_kernel<<<eblocks, 256, 0, stream>>>(rows, cols, offsets, rank, sortedPair);

    const int nblocks = (N_NODES * 64 + 255) / 256;      // 1 wave per node
    node_agg_kernel<<<nblocks, 256, 0, stream>>>(Q, Kb, Vb, offsets, counts,
                                                 sortedPair, attOut, normArr, res);

    norm_edge_kernel<<<eblocks, 256, 0, stream>>>(rows, normArr, attOut);
}